// Round 6
// baseline (197.579 us; speedup 1.0000x reference)
//
#include <hip/hip_runtime.h>
#include <hip/hip_bf16.h>

typedef __attribute__((ext_vector_type(8))) short short8;
typedef __attribute__((ext_vector_type(4))) short short4v;
typedef __attribute__((ext_vector_type(4))) float f32x4;

#define BB 2
#define LL 2048
#define DD 1024
#define HH 16
#define DHH 64
#define KK 1024

__device__ __forceinline__ void gload_lds16(const void* g, void* l) {
  __builtin_amdgcn_global_load_lds((const __attribute__((address_space(1))) void*)g,
                                   (__attribute__((address_space(3))) void*)l,
                                   16, 0, 0);
}

__device__ __forceinline__ f32x4 splat4(float x) {
  f32x4 v; v[0] = x; v[1] = x; v[2] = x; v[3] = x; return v;
}

__device__ __forceinline__ unsigned short f2b(float x) {
  __hip_bfloat16 h = __float2bfloat16(x);
  return *reinterpret_cast<unsigned short*>(&h);
}

// fused fp32 -> bf16 convert for x, w_in, w_out (one launch)
#define NX8  ((BB * LL * DD) / 8)      // 524288
#define NWI8 ((3 * DD * DD) / 8)       // 393216
#define NWO8 ((DD * DD) / 8)           // 131072
__global__ void cvt_all(const float* __restrict__ x,
                        const float* __restrict__ w_in,
                        const float* __restrict__ w_out,
                        __hip_bfloat16* __restrict__ xb,
                        __hip_bfloat16* __restrict__ w_inb,
                        __hip_bfloat16* __restrict__ w_outb) {
  int i = blockIdx.x * blockDim.x + threadIdx.x;
  const float* src;
  __hip_bfloat16* dst;
  int j;
  if (i < NX8)              { src = x;     dst = xb;     j = i; }
  else if (i < NX8 + NWI8)  { src = w_in;  dst = w_inb;  j = i - NX8; }
  else                      { src = w_out; dst = w_outb; j = i - NX8 - NWI8; }
  const f32x4 a = ((const f32x4*)src)[j * 2];
  const f32x4 b = ((const f32x4*)src)[j * 2 + 1];
  short8 o;
#pragma unroll
  for (int k = 0; k < 4; ++k) o[k] = (short)f2b(a[k]);
#pragma unroll
  for (int k = 0; k < 4; ++k) o[4 + k] = (short)f2b(b[k]);
  ((short8*)dst)[j] = o;
}

// C = A @ B^T (+bias). A: MxK bf16 row-major, B: NxK bf16 row-major. K=1024.
// QKV mode scatters into Q/K (B,H,L,DH) and V TRANSPOSED (B,H,DH,L), bf16.
// Direct mode writes fp32 C[m*N+n].
template<bool QKV>
__global__ void gemm_bt(const __hip_bfloat16* __restrict__ A,
                        const __hip_bfloat16* __restrict__ Bm,
                        const float* __restrict__ bias,
                        __hip_bfloat16* __restrict__ Cq,
                        __hip_bfloat16* __restrict__ Ck,
                        __hip_bfloat16* __restrict__ Cv,
                        float* __restrict__ Cd,
                        int N, int nbn) {
  __shared__ __align__(16) char As[8192];
  __shared__ __align__(16) char Bs[8192];
  const int tid = threadIdx.x;
  const int lane = tid & 63, wid = tid >> 6;
  const int l15 = lane & 15, lhi = lane >> 4;
  const int wm = wid >> 1, wn = wid & 1;
  const int bn = blockIdx.x % nbn, bm = blockIdx.x / nbn;
  const int m0 = bm * 128, n0 = bn * 128;

  f32x4 acc[4][4] = {};

  for (int kt = 0; kt < KK / 32; ++kt) {
    const int k0 = kt * 32;
    __syncthreads();
#pragma unroll
    for (int j = 0; j < 2; ++j) {
      int c = wid * 128 + j * 64 + lane;       // 16B chunk index
      int row = c >> 2;
      int ab = ((c & 3) * 16) ^ (((row >> 1) & 3) << 4);
      gload_lds16(A + (size_t)(m0 + row) * KK + k0 + (ab >> 1),
                  As + wid * 2048 + j * 1024);
    }
#pragma unroll
    for (int j = 0; j < 2; ++j) {
      int c = wid * 128 + j * 64 + lane;
      int row = c >> 2;
      int ab = ((c & 3) * 16) ^ (((row >> 1) & 3) << 4);
      gload_lds16(Bm + (size_t)(n0 + row) * KK + k0 + (ab >> 1),
                  Bs + wid * 2048 + j * 1024);
    }
    __syncthreads();

    short8 af[4], bf[4];
#pragma unroll
    for (int mf = 0; mf < 4; ++mf) {
      int row = wm * 64 + mf * 16 + l15;
      int byt = (lhi * 16) ^ (((row >> 1) & 3) << 4);
      af[mf] = *(const short8*)(As + row * 64 + byt);
    }
#pragma unroll
    for (int nf = 0; nf < 4; ++nf) {
      int row = wn * 64 + nf * 16 + l15;
      int byt = (lhi * 16) ^ (((row >> 1) & 3) << 4);
      bf[nf] = *(const short8*)(Bs + row * 64 + byt);
    }
#pragma unroll
    for (int mf = 0; mf < 4; ++mf)
#pragma unroll
      for (int nf = 0; nf < 4; ++nf)
        acc[mf][nf] = __builtin_amdgcn_mfma_f32_16x16x32_bf16(af[mf], bf[nf],
                                                              acc[mf][nf], 0, 0, 0);
  }

  // epilogue: C/D layout col=lane&15, row=(lane>>4)*4+reg
#pragma unroll
  for (int mf = 0; mf < 4; ++mf) {
#pragma unroll
    for (int nf = 0; nf < 4; ++nf) {
      const int n = n0 + wn * 64 + nf * 16 + l15;
      if constexpr (QKV) {
        const int sect = n >> 10;          // 0=q 1=k 2=v
        const int nn = n & 1023;
        const int h = nn >> 6, dh = nn & 63;
        const float bv = bias[n];
        const int m_base = m0 + wm * 64 + mf * 16 + lhi * 4;   // +r, same 2k page
        const int b = m_base >> 11, ml = m_base & 2047;
        if (sect == 2) {
          // V transposed: [b*H+h][dh][l]; 4 r-values are l-contiguous -> 8B store
          short4v v;
#pragma unroll
          for (int r = 0; r < 4; ++r) v[r] = (short)f2b(acc[mf][nf][r] + bv);
          *(short4v*)&Cv[(((size_t)(b * HH + h)) * DHH + dh) * LL + ml] = v;
        } else {
          __hip_bfloat16* dst = (sect == 0) ? Cq : Ck;
#pragma unroll
          for (int r = 0; r < 4; ++r)
            dst[(((size_t)(b * HH + h)) * LL + ml + r) * DHH + dh] =
                __float2bfloat16(acc[mf][nf][r] + bv);
        }
      } else {
#pragma unroll
        for (int r = 0; r < 4; ++r) {
          const int m = m0 + wm * 64 + mf * 16 + lhi * 4 + r;
          Cd[(size_t)m * N + n] = acc[mf][nf][r];
        }
      }
    }
  }
}

// Flash attention: 4096 one-wave blocks. Block = 16 q-rows of one head.
// No barriers, no K/V LDS staging (L2-resident); P via 2KB wave-private LDS.
__global__ __launch_bounds__(64) void attn_fwd(
    const __hip_bfloat16* __restrict__ Q,
    const __hip_bfloat16* __restrict__ K,
    const __hip_bfloat16* __restrict__ VT,
    __hip_bfloat16* __restrict__ att,
    const int* __restrict__ maskp) {
  __shared__ __align__(16) char Pw[2048];   // [row16][128B], byte^=((row&12)<<3)
  const int lane = threadIdx.x;             // 0..63
  const int l15 = lane & 15, lhi = lane >> 4;
  const int bid = blockIdx.x;
  const int strip = 127 - (bid >> 5);       // heavy strips dispatched first
  const int bh = bid & 31;                  // head pinned to one XCD's L2
  const int causal = *maskp;
  const int r0 = strip * 16;
  const __hip_bfloat16* Qg = Q + (size_t)bh * LL * DHH;
  const __hip_bfloat16* Kg = K + (size_t)bh * LL * DHH;
  const __hip_bfloat16* VTg = VT + (size_t)bh * DHH * LL;

  // Q fragments in registers for the whole block (16 rows)
  short8 aq[2];
#pragma unroll
  for (int ks = 0; ks < 2; ++ks)
    aq[ks] = *(const short8*)(Qg + (size_t)(r0 + l15) * DHH + ks * 32 + lhi * 8);

  f32x4 o[4] = {};
  f32x4 mrun = splat4(-1e30f), lrun = splat4(0.0f);

  const int nt = causal ? ((r0 + 15) >> 6) + 1 : (LL / 64);

  for (int t = 0; t < nt; ++t) {
    const int kv0 = t * 64;
    // K fragments direct from global (B-operand: col=kv, k=dh)
    short8 bk[4][2];
#pragma unroll
    for (int nf = 0; nf < 4; ++nf)
#pragma unroll
      for (int ks = 0; ks < 2; ++ks)
        bk[nf][ks] = *(const short8*)(Kg + (size_t)(kv0 + nf * 16 + l15) * DHH +
                                      ks * 32 + lhi * 8);
    // V^T fragments issued early; consumed after softmax (latency hidden)
    short8 bv[4][2];
#pragma unroll
    for (int nf = 0; nf < 4; ++nf)
#pragma unroll
      for (int ks = 0; ks < 2; ++ks)
        bv[nf][ks] = *(const short8*)(VTg + (size_t)(nf * 16 + l15) * LL +
                                      kv0 + ks * 32 + lhi * 8);

    // QK^T
    f32x4 s[4] = {};
    __builtin_amdgcn_s_setprio(1);
#pragma unroll
    for (int nf = 0; nf < 4; ++nf) {
      s[nf] = __builtin_amdgcn_mfma_f32_16x16x32_bf16(aq[0], bk[nf][0], s[nf], 0, 0, 0);
      s[nf] = __builtin_amdgcn_mfma_f32_16x16x32_bf16(aq[1], bk[nf][1], s[nf], 0, 0, 0);
    }
    __builtin_amdgcn_s_setprio(0);

    // scale + causal mask
    const bool needmask = causal && (kv0 + 63 > r0);
#pragma unroll
    for (int nf = 0; nf < 4; ++nf) {
      const int kv = kv0 + nf * 16 + l15;
#pragma unroll
      for (int r = 0; r < 4; ++r) {
        float v = s[nf][r] * 0.125f;   // 1/sqrt(64)
        if (needmask && kv > r0 + lhi * 4 + r) v = -1e30f;
        s[nf][r] = v;
      }
    }
    // online softmax (rows = lhi*4+r, reduce over 16 l15 lanes + nf regs)
    {
      f32x4 pm = s[0];
#pragma unroll
      for (int nf = 1; nf < 4; ++nf)
#pragma unroll
        for (int r = 0; r < 4; ++r) pm[r] = fmaxf(pm[r], s[nf][r]);
#pragma unroll
      for (int d = 1; d < 16; d <<= 1)
#pragma unroll
        for (int r = 0; r < 4; ++r) pm[r] = fmaxf(pm[r], __shfl_xor(pm[r], d, 64));

      f32x4 mnew, rsum;
#pragma unroll
      for (int r = 0; r < 4; ++r) {
        mnew[r] = fmaxf(mrun[r], pm[r]);
        float sc = __expf(mrun[r] - mnew[r]);
        lrun[r] *= sc;
        rsum[r] = 0.0f;
#pragma unroll
        for (int nf = 0; nf < 4; ++nf) o[nf][r] *= sc;
      }
#pragma unroll
      for (int nf = 0; nf < 4; ++nf)
#pragma unroll
        for (int r = 0; r < 4; ++r) {
          float p = __expf(s[nf][r] - mnew[r]);
          s[nf][r] = p;
          rsum[r] += p;
        }
#pragma unroll
      for (int d = 1; d < 16; d <<= 1)
#pragma unroll
        for (int r = 0; r < 4; ++r) rsum[r] += __shfl_xor(rsum[r], d, 64);
#pragma unroll
      for (int r = 0; r < 4; ++r) lrun[r] += rsum[r];
      mrun = mnew;
    }
    // P -> wave-private LDS (swizzled), then reload as PV A-operand
#pragma unroll
    for (int nf = 0; nf < 4; ++nf)
#pragma unroll
      for (int r = 0; r < 4; ++r) {
        const int row = lhi * 4 + r;
        const int cb = (nf * 16 + l15) * 2;
        *(__hip_bfloat16*)(Pw + row * 128 + (cb ^ ((row & 12) << 3))) =
            __float2bfloat16(s[nf][r]);
      }
    short8 ap[2];
#pragma unroll
    for (int ks = 0; ks < 2; ++ks) {
      const int row = l15;
      const int cb = ks * 64 + lhi * 16;
      ap[ks] = *(const short8*)(Pw + row * 128 + (cb ^ ((row & 12) << 3)));
    }
    // PV
    __builtin_amdgcn_s_setprio(1);
#pragma unroll
    for (int nf = 0; nf < 4; ++nf) {
      o[nf] = __builtin_amdgcn_mfma_f32_16x16x32_bf16(ap[0], bv[nf][0], o[nf], 0, 0, 0);
      o[nf] = __builtin_amdgcn_mfma_f32_16x16x32_bf16(ap[1], bv[nf][1], o[nf], 0, 0, 0);
    }
    __builtin_amdgcn_s_setprio(0);
  }

  // finalize: att layout (B, L, H*DH) merged heads
  const int b = bh >> 4, h = bh & 15;
#pragma unroll
  for (int r = 0; r < 4; ++r) {
    const int row = r0 + lhi * 4 + r;
    const float inv = 1.0f / lrun[r];
#pragma unroll
    for (int nf = 0; nf < 4; ++nf)
      att[((size_t)(b * LL + row)) * DD + h * DHH + nf * 16 + l15] =
          __float2bfloat16(o[nf][r] * inv);
  }
}

extern "C" void kernel_launch(void* const* d_in, const int* in_sizes, int n_in,
                              void* d_out, int out_size, void* d_ws, size_t ws_size,
                              hipStream_t stream) {
  const float* x     = (const float*)d_in[0];
  const float* w_in  = (const float*)d_in[1];
  const float* b_in  = (const float*)d_in[2];
  const float* w_out = (const float*)d_in[3];
  const int* mask    = (const int*)d_in[4];
  float* out = (float*)d_out;

  char* ws = (char*)d_ws;
  const size_t MiB = 1024u * 1024u;
  __hip_bfloat16* xb    = (__hip_bfloat16*)(ws);             // 8 MiB
  __hip_bfloat16* w_inb = (__hip_bfloat16*)(ws + 8 * MiB);   // 6 MiB
  __hip_bfloat16* w_outb= (__hip_bfloat16*)(ws + 14 * MiB);  // 2 MiB
  __hip_bfloat16* Qb    = (__hip_bfloat16*)(ws + 16 * MiB);  // 8 MiB
  __hip_bfloat16* Kb    = (__hip_bfloat16*)(ws + 24 * MiB);  // 8 MiB
  __hip_bfloat16* Vtb   = (__hip_bfloat16*)(ws + 32 * MiB);  // 8 MiB (transposed)
  __hip_bfloat16* att   = (__hip_bfloat16*)(ws + 40 * MiB);  // 8 MiB

  // fused conversions: (524288+393216+131072)/256 = 4096 blocks
  cvt_all<<<dim3(4096), dim3(256), 0, stream>>>(x, w_in, w_out, xb, w_inb, w_outb);

  gemm_bt<true><<<dim3(32 * 24), dim3(256), 0, stream>>>(
      xb, w_inb, b_in, Qb, Kb, Vtb, nullptr, 3072, 24);
  attn_fwd<<<dim3(4096), dim3(64), 0, stream>>>(Qb, Kb, Vtb, att, mask);
  gemm_bt<false><<<dim3(32 * 8), dim3(256), 0, stream>>>(
      att, w_outb, nullptr, nullptr, nullptr, nullptr, out, 1024, 8);
}

// Round 7
// 139.548 us; speedup vs baseline: 1.4158x; 1.4158x over previous
//
#include <hip/hip_runtime.h>
#include <hip/hip_bf16.h>

typedef __attribute__((ext_vector_type(8))) short short8;
typedef __attribute__((ext_vector_type(4))) short short4v;
typedef __attribute__((ext_vector_type(4))) float f32x4;

#define BB 2
#define LL 2048
#define DD 1024
#define HH 16
#define DHH 64
#define KK 1024

__device__ __forceinline__ void gload_lds16(const void* g, void* l) {
  __builtin_amdgcn_global_load_lds((const __attribute__((address_space(1))) void*)g,
                                   (__attribute__((address_space(3))) void*)l,
                                   16, 0, 0);
}

__device__ __forceinline__ f32x4 splat4(float x) {
  f32x4 v; v[0] = x; v[1] = x; v[2] = x; v[3] = x; return v;
}

__device__ __forceinline__ unsigned short f2b(float x) {
  __hip_bfloat16 h = __float2bfloat16(x);
  return *reinterpret_cast<unsigned short*>(&h);
}

// fused fp32 -> bf16 convert for x, w_in, w_out (one launch)
#define NX8  ((BB * LL * DD) / 8)      // 524288
#define NWI8 ((3 * DD * DD) / 8)       // 393216
#define NWO8 ((DD * DD) / 8)           // 131072
__global__ void cvt_all(const float* __restrict__ x,
                        const float* __restrict__ w_in,
                        const float* __restrict__ w_out,
                        __hip_bfloat16* __restrict__ xb,
                        __hip_bfloat16* __restrict__ w_inb,
                        __hip_bfloat16* __restrict__ w_outb) {
  int i = blockIdx.x * blockDim.x + threadIdx.x;
  const float* src;
  __hip_bfloat16* dst;
  int j;
  if (i < NX8)              { src = x;     dst = xb;     j = i; }
  else if (i < NX8 + NWI8)  { src = w_in;  dst = w_inb;  j = i - NX8; }
  else                      { src = w_out; dst = w_outb; j = i - NX8 - NWI8; }
  const f32x4 a = ((const f32x4*)src)[j * 2];
  const f32x4 b = ((const f32x4*)src)[j * 2 + 1];
  short8 o;
#pragma unroll
  for (int k = 0; k < 4; ++k) o[k] = (short)f2b(a[k]);
#pragma unroll
  for (int k = 0; k < 4; ++k) o[4 + k] = (short)f2b(b[k]);
  ((short8*)dst)[j] = o;
}

// C = A @ B^T (+bias). A: MxK bf16 row-major, B: NxK bf16 row-major. K=1024.
// QKV mode scatters into Q/K (B,H,L,DH) and V TRANSPOSED (B,H,DH,L), bf16.
// Direct mode writes fp32 C[m*N+n].
template<bool QKV>
__global__ void gemm_bt(const __hip_bfloat16* __restrict__ A,
                        const __hip_bfloat16* __restrict__ Bm,
                        const float* __restrict__ bias,
                        __hip_bfloat16* __restrict__ Cq,
                        __hip_bfloat16* __restrict__ Ck,
                        __hip_bfloat16* __restrict__ Cv,
                        float* __restrict__ Cd,
                        int N, int nbn) {
  __shared__ __align__(16) char As[8192];
  __shared__ __align__(16) char Bs[8192];
  const int tid = threadIdx.x;
  const int lane = tid & 63, wid = tid >> 6;
  const int l15 = lane & 15, lhi = lane >> 4;
  const int wm = wid >> 1, wn = wid & 1;
  const int bn = blockIdx.x % nbn, bm = blockIdx.x / nbn;
  const int m0 = bm * 128, n0 = bn * 128;

  f32x4 acc[4][4] = {};

  for (int kt = 0; kt < KK / 32; ++kt) {
    const int k0 = kt * 32;
    __syncthreads();
#pragma unroll
    for (int j = 0; j < 2; ++j) {
      int c = wid * 128 + j * 64 + lane;       // 16B chunk index
      int row = c >> 2;
      int ab = ((c & 3) * 16) ^ (((row >> 1) & 3) << 4);
      gload_lds16(A + (size_t)(m0 + row) * KK + k0 + (ab >> 1),
                  As + wid * 2048 + j * 1024);
    }
#pragma unroll
    for (int j = 0; j < 2; ++j) {
      int c = wid * 128 + j * 64 + lane;
      int row = c >> 2;
      int ab = ((c & 3) * 16) ^ (((row >> 1) & 3) << 4);
      gload_lds16(Bm + (size_t)(n0 + row) * KK + k0 + (ab >> 1),
                  Bs + wid * 2048 + j * 1024);
    }
    __syncthreads();

    short8 af[4], bf[4];
#pragma unroll
    for (int mf = 0; mf < 4; ++mf) {
      int row = wm * 64 + mf * 16 + l15;
      int byt = (lhi * 16) ^ (((row >> 1) & 3) << 4);
      af[mf] = *(const short8*)(As + row * 64 + byt);
    }
#pragma unroll
    for (int nf = 0; nf < 4; ++nf) {
      int row = wn * 64 + nf * 16 + l15;
      int byt = (lhi * 16) ^ (((row >> 1) & 3) << 4);
      bf[nf] = *(const short8*)(Bs + row * 64 + byt);
    }
#pragma unroll
    for (int mf = 0; mf < 4; ++mf)
#pragma unroll
      for (int nf = 0; nf < 4; ++nf)
        acc[mf][nf] = __builtin_amdgcn_mfma_f32_16x16x32_bf16(af[mf], bf[nf],
                                                              acc[mf][nf], 0, 0, 0);
  }

  // epilogue: C/D layout col=lane&15, row=(lane>>4)*4+reg
#pragma unroll
  for (int mf = 0; mf < 4; ++mf) {
#pragma unroll
    for (int nf = 0; nf < 4; ++nf) {
      const int n = n0 + wn * 64 + nf * 16 + l15;
      if constexpr (QKV) {
        const int sect = n >> 10;          // 0=q 1=k 2=v
        const int nn = n & 1023;
        const int h = nn >> 6, dh = nn & 63;
        const float bv = bias[n];
        const int m_base = m0 + wm * 64 + mf * 16 + lhi * 4;   // +r, same 2k page
        const int b = m_base >> 11, ml = m_base & 2047;
        if (sect == 2) {
          // V transposed: [b*H+h][dh][l]; 4 r-values are l-contiguous -> 8B store
          short4v v;
#pragma unroll
          for (int r = 0; r < 4; ++r) v[r] = (short)f2b(acc[mf][nf][r] + bv);
          *(short4v*)&Cv[(((size_t)(b * HH + h)) * DHH + dh) * LL + ml] = v;
        } else {
          __hip_bfloat16* dst = (sect == 0) ? Cq : Ck;
#pragma unroll
          for (int r = 0; r < 4; ++r)
            dst[(((size_t)(b * HH + h)) * LL + ml + r) * DHH + dh] =
                __float2bfloat16(acc[mf][nf][r] + bv);
        }
      } else {
#pragma unroll
        for (int r = 0; r < 4; ++r) {
          const int m = m0 + wm * 64 + mf * 16 + lhi * 4 + r;
          Cd[(size_t)m * N + n] = acc[mf][nf][r];
        }
      }
    }
  }
}

// Flash attention, split-KV: 2048 blocks x 2 waves. Block = 32 q-rows of one
// head; wave 0 takes kv-tiles [0,hf), wave 1 takes [hf,nt); partials merged
// in-block via LDS. No K/V LDS staging (L2-resident).
__global__ __launch_bounds__(128) void attn_fwd(
    const __hip_bfloat16* __restrict__ Q,
    const __hip_bfloat16* __restrict__ K,
    const __hip_bfloat16* __restrict__ VT,
    __hip_bfloat16* __restrict__ att,
    const int* __restrict__ maskp) {
  __shared__ __align__(16) char Pbuf[2][4096];  // per-wave P [row32][128B], byte^=((row&12)<<3)
  __shared__ __align__(16) float Ob[32][68];    // wave-1 partial O (padded)
  __shared__ float Mb[32], Lb[32];              // wave-1 partial m, l
  const int tid = threadIdx.x;
  const int lane = tid & 63, wid = tid >> 6;
  const int l15 = lane & 15, lhi = lane >> 4;
  const int bid = blockIdx.x;
  const int strip = 63 - (bid >> 5);        // heavy strips dispatched first
  const int bh = bid & 31;                  // head pinned to one XCD's L2
  const int causal = *maskp;
  const int r0 = strip * 32;
  const __hip_bfloat16* Qg = Q + (size_t)bh * LL * DHH;
  const __hip_bfloat16* Kg = K + (size_t)bh * LL * DHH;
  const __hip_bfloat16* VTg = VT + (size_t)bh * DHH * LL;
  char* Pw = Pbuf[wid];

  // Q fragments in registers (both waves load the same strip)
  short8 aq[2][2];
#pragma unroll
  for (int mf = 0; mf < 2; ++mf)
#pragma unroll
    for (int ks = 0; ks < 2; ++ks)
      aq[mf][ks] = *(const short8*)(Qg + (size_t)(r0 + mf * 16 + l15) * DHH +
                                    ks * 32 + lhi * 8);

  f32x4 o[2][4] = {};
  f32x4 mrun[2], lrun[2];
  mrun[0] = splat4(-1e30f); mrun[1] = splat4(-1e30f);
  lrun[0] = splat4(0.0f);   lrun[1] = splat4(0.0f);

  const int nt = causal ? ((r0 + 31) >> 6) + 1 : (LL / 64);
  const int hf = (nt + 1) >> 1;             // wave 0: [0,hf)  wave 1: [hf,nt)
  const int t0 = wid ? hf : 0;
  const int t1 = wid ? nt : hf;

  for (int t = t0; t < t1; ++t) {
    const int kv0 = t * 64;
    // K fragments direct from global (B-operand: col=kv, k=dh)
    short8 bk[4][2];
#pragma unroll
    for (int nf = 0; nf < 4; ++nf)
#pragma unroll
      for (int ks = 0; ks < 2; ++ks)
        bk[nf][ks] = *(const short8*)(Kg + (size_t)(kv0 + nf * 16 + l15) * DHH +
                                      ks * 32 + lhi * 8);
    // V^T fragments issued early; consumed after softmax (latency hidden)
    short8 bv[4][2];
#pragma unroll
    for (int nf = 0; nf < 4; ++nf)
#pragma unroll
      for (int ks = 0; ks < 2; ++ks)
        bv[nf][ks] = *(const short8*)(VTg + (size_t)(nf * 16 + l15) * LL +
                                      kv0 + ks * 32 + lhi * 8);

    // QK^T
    f32x4 s[2][4] = {};
    __builtin_amdgcn_s_setprio(1);
#pragma unroll
    for (int mf = 0; mf < 2; ++mf)
#pragma unroll
      for (int nf = 0; nf < 4; ++nf) {
        s[mf][nf] = __builtin_amdgcn_mfma_f32_16x16x32_bf16(aq[mf][0], bk[nf][0], s[mf][nf], 0, 0, 0);
        s[mf][nf] = __builtin_amdgcn_mfma_f32_16x16x32_bf16(aq[mf][1], bk[nf][1], s[mf][nf], 0, 0, 0);
      }
    __builtin_amdgcn_s_setprio(0);

    // scale + causal mask
    const bool needmask = causal && (kv0 + 63 > r0);
#pragma unroll
    for (int mf = 0; mf < 2; ++mf)
#pragma unroll
      for (int nf = 0; nf < 4; ++nf) {
        const int kv = kv0 + nf * 16 + l15;
#pragma unroll
        for (int r = 0; r < 4; ++r) {
          float v = s[mf][nf][r] * 0.125f;   // 1/sqrt(64)
          if (needmask && kv > r0 + mf * 16 + lhi * 4 + r) v = -1e30f;
          s[mf][nf][r] = v;
        }
      }
    // online softmax
#pragma unroll
    for (int mf = 0; mf < 2; ++mf) {
      f32x4 pm = s[mf][0];
#pragma unroll
      for (int nf = 1; nf < 4; ++nf)
#pragma unroll
        for (int r = 0; r < 4; ++r) pm[r] = fmaxf(pm[r], s[mf][nf][r]);
#pragma unroll
      for (int d = 1; d < 16; d <<= 1)
#pragma unroll
        for (int r = 0; r < 4; ++r) pm[r] = fmaxf(pm[r], __shfl_xor(pm[r], d, 64));

      f32x4 mnew, rsum;
#pragma unroll
      for (int r = 0; r < 4; ++r) {
        mnew[r] = fmaxf(mrun[mf][r], pm[r]);
        float sc = __expf(mrun[mf][r] - mnew[r]);
        lrun[mf][r] *= sc;
        rsum[r] = 0.0f;
#pragma unroll
        for (int nf = 0; nf < 4; ++nf) o[mf][nf][r] *= sc;
      }
#pragma unroll
      for (int nf = 0; nf < 4; ++nf)
#pragma unroll
        for (int r = 0; r < 4; ++r) {
          float p = __expf(s[mf][nf][r] - mnew[r]);
          s[mf][nf][r] = p;
          rsum[r] += p;
        }
#pragma unroll
      for (int d = 1; d < 16; d <<= 1)
#pragma unroll
        for (int r = 0; r < 4; ++r) rsum[r] += __shfl_xor(rsum[r], d, 64);
#pragma unroll
      for (int r = 0; r < 4; ++r) lrun[mf][r] += rsum[r];
      mrun[mf] = mnew;
    }
    // P -> wave-private LDS (swizzled), then reload as PV A-operand
#pragma unroll
    for (int mf = 0; mf < 2; ++mf)
#pragma unroll
      for (int nf = 0; nf < 4; ++nf)
#pragma unroll
        for (int r = 0; r < 4; ++r) {
          const int row = mf * 16 + lhi * 4 + r;
          const int cb = (nf * 16 + l15) * 2;
          *(__hip_bfloat16*)(Pw + row * 128 + (cb ^ ((row & 12) << 3))) =
              __float2bfloat16(s[mf][nf][r]);
        }
    short8 ap[2][2];
#pragma unroll
    for (int mf = 0; mf < 2; ++mf)
#pragma unroll
      for (int ks = 0; ks < 2; ++ks) {
        const int row = mf * 16 + l15;
        const int cb = ks * 64 + lhi * 16;
        ap[mf][ks] = *(const short8*)(Pw + row * 128 + (cb ^ ((row & 12) << 3)));
      }
    // PV
    __builtin_amdgcn_s_setprio(1);
#pragma unroll
    for (int mf = 0; mf < 2; ++mf)
#pragma unroll
      for (int nf = 0; nf < 4; ++nf) {
        o[mf][nf] = __builtin_amdgcn_mfma_f32_16x16x32_bf16(ap[mf][0], bv[nf][0], o[mf][nf], 0, 0, 0);
        o[mf][nf] = __builtin_amdgcn_mfma_f32_16x16x32_bf16(ap[mf][1], bv[nf][1], o[mf][nf], 0, 0, 0);
      }
    __builtin_amdgcn_s_setprio(0);
  }

  // merge the two kv-half partials (flash combine), then store
  __syncthreads();
  if (wid == 1) {
#pragma unroll
    for (int mf = 0; mf < 2; ++mf)
#pragma unroll
      for (int r = 0; r < 4; ++r) {
        const int row = mf * 16 + lhi * 4 + r;
        if (l15 == 0) { Mb[row] = mrun[mf][r]; Lb[row] = lrun[mf][r]; }
#pragma unroll
        for (int nf = 0; nf < 4; ++nf)
          Ob[row][nf * 16 + l15] = o[mf][nf][r];
      }
  }
  __syncthreads();
  if (wid == 0) {
    const int b = bh >> 4, h = bh & 15;
#pragma unroll
    for (int mf = 0; mf < 2; ++mf)
#pragma unroll
      for (int r = 0; r < 4; ++r) {
        const int row = mf * 16 + lhi * 4 + r;
        const float m1 = Mb[row], l1 = Lb[row];
        const float m0 = mrun[mf][r], l0 = lrun[mf][r];
        const float mt = fmaxf(m0, m1);
        const float sc0 = __expf(m0 - mt), sc1 = __expf(m1 - mt);
        const float inv = 1.0f / (l0 * sc0 + l1 * sc1);
        const int grow = r0 + row;
#pragma unroll
        for (int nf = 0; nf < 4; ++nf)
          att[((size_t)(b * LL + grow)) * DD + h * DHH + nf * 16 + l15] =
              __float2bfloat16((o[mf][nf][r] * sc0 + Ob[row][nf * 16 + l15] * sc1) * inv);
      }
  }
}

extern "C" void kernel_launch(void* const* d_in, const int* in_sizes, int n_in,
                              void* d_out, int out_size, void* d_ws, size_t ws_size,
                              hipStream_t stream) {
  const float* x     = (const float*)d_in[0];
  const float* w_in  = (const float*)d_in[1];
  const float* b_in  = (const float*)d_in[2];
  const float* w_out = (const float*)d_in[3];
  const int* mask    = (const int*)d_in[4];
  float* out = (float*)d_out;

  char* ws = (char*)d_ws;
  const size_t MiB = 1024u * 1024u;
  __hip_bfloat16* xb    = (__hip_bfloat16*)(ws);             // 8 MiB
  __hip_bfloat16* w_inb = (__hip_bfloat16*)(ws + 8 * MiB);   // 6 MiB
  __hip_bfloat16* w_outb= (__hip_bfloat16*)(ws + 14 * MiB);  // 2 MiB
  __hip_bfloat16* Qb    = (__hip_bfloat16*)(ws + 16 * MiB);  // 8 MiB
  __hip_bfloat16* Kb    = (__hip_bfloat16*)(ws + 24 * MiB);  // 8 MiB
  __hip_bfloat16* Vtb   = (__hip_bfloat16*)(ws + 32 * MiB);  // 8 MiB (transposed)
  __hip_bfloat16* att   = (__hip_bfloat16*)(ws + 40 * MiB);  // 8 MiB

  // fused conversions: (524288+393216+131072)/256 = 4096 blocks
  cvt_all<<<dim3(4096), dim3(256), 0, stream>>>(x, w_in, w_out, xb, w_inb, w_outb);

  gemm_bt<true><<<dim3(32 * 24), dim3(256), 0, stream>>>(
      xb, w_inb, b_in, Qb, Kb, Vtb, nullptr, 3072, 24);
  attn_fwd<<<dim3(2048), dim3(128), 0, stream>>>(Qb, Kb, Vtb, att, mask);
  gemm_bt<false><<<dim3(32 * 8), dim3(256), 0, stream>>>(
      att, w_outb, nullptr, nullptr, nullptr, nullptr, out, 1024, 8);
}